// Round 11
// baseline (234.190 us; speedup 1.0000x reference)
//
#include <hip/hip_runtime.h>
#include <math.h>

#define TV 3200          // T*V = 128*25
#define NTV 204800       // N*T*V
#define NB1 512          // k_pw blocks: 64 n x 8 q (16-t tile + 2 halo slices each side)
#define NB2 400          // k_h blocks: float2 sites, 400*256 = NTV/2
#define NB3 800          // k_out blocks: (f4-site, o-quarter), 800*256 = NTV/4 * 4
constexpr float EPSF = 1e-5f;

typedef float f2 __attribute__((ext_vector_type(2)));
typedef float f4 __attribute__((ext_vector_type(4)));

// fast tanh: 1 - 2/(e^{2x}+1); exact saturation, ~1e-7 abs err in operating range
__device__ inline float fast_tanh(float x){
  float e = __expf(2.f*x);
  return 1.f - 2.f/(e + 1.f);
}

// 4-wave (256-thread) partial writer; leading sync protects lds scratch reuse
template<int NS>
__device__ inline void write_partials4(float (&vals)[NS], float* __restrict__ outp, int nb, float* lds){
  __syncthreads();
  int lane = threadIdx.x & 63, wid = threadIdx.x >> 6;
  #pragma unroll
  for (int s = 0; s < NS; ++s){
    float v = vals[s];
    #pragma unroll
    for (int o = 32; o > 0; o >>= 1) v += __shfl_down(v, o);
    if (lane == 0) lds[s*4 + wid] = v;
  }
  __syncthreads();
  if ((int)threadIdx.x < NS)
    outp[threadIdx.x*nb + blockIdx.x] = lds[threadIdx.x*4+0] + lds[threadIdx.x*4+1]
                                      + lds[threadIdx.x*4+2] + lds[threadIdx.x*4+3];
}

// 8-wave (512-thread) partial writer
template<int NS>
__device__ inline void write_partials8(float (&vals)[NS], float* __restrict__ outp, int nb, float* lds){
  __syncthreads();
  int lane = threadIdx.x & 63, wid = threadIdx.x >> 6;   // 0..7
  #pragma unroll
  for (int s = 0; s < NS; ++s){
    float v = vals[s];
    #pragma unroll
    for (int o = 32; o > 0; o >>= 1) v += __shfl_down(v, o);
    if (lane == 0) lds[s*8 + wid] = v;
  }
  __syncthreads();
  if ((int)threadIdx.x < NS){
    float t = 0.f;
    #pragma unroll
    for (int w = 0; w < 8; ++w) t += lds[threadIdx.x*8 + w];
    outp[threadIdx.x*nb + blockIdx.x] = t;
  }
}

// ==== K1: fused proj + wat. Block = (n, 16-t tile) x 512 threads, ONE site/thread.
// 16 waves/CU (4/SIMD) for latency hiding. v0,s in LDS (halo recomputed).
__global__ __launch_bounds__(512) void k_pw(
    const float* __restrict__ x,
    const float* __restrict__ Wv, const float* __restrict__ bv,
    const float* __restrict__ Wr, const float* __restrict__ br,
    const float* __restrict__ Ww, const float* __restrict__ bw,
    float* __restrict__ r0, float* __restrict__ att,
    float* __restrict__ pr, float* __restrict__ patt)
{
  __shared__ float sV[500*9];         // v0: 20 slices x 25 v, r-dim padded to 9
  __shared__ float sS[500];           // s tile
  __shared__ float sWvr[1024];        // [c][0..7]=Wv[r][c], [c][8..15]=Wr[r][c]
  __shared__ float sWw[125], sbw[25];
  __shared__ float red[16*8];
  const int tid = threadIdx.x;
  const int b = blockIdx.x, n = b >> 3, q = b & 7;
  const int t0 = q*16;
  for (int i2 = tid; i2 < 1024; i2 += 512){
    int c = i2 >> 4, k = i2 & 15;
    sWvr[i2] = (k < 8) ? Wv[k*64 + c] : Wr[(k-8)*64 + c];
  }
  if (tid < 125) sWw[tid] = Ww[tid];
  if (tid < 25)  sbw[tid] = bw[tid];
  __syncthreads();

  const int site = tid;                // 0..499 active
  const bool act = (site < 500);
  const bool val = act && (q > 0 || site >= 50) && (q < 7 || site < 450);
  const bool own = act && (site >= 50) && (site < 450);   // owned slices [2,18)
  const float* xpn = x + (size_t)n*64*TV + (t0*25 - 50);
  const f4* sW4 = (const f4*)sWvr;

  float av[8]={0,0,0,0,0,0,0,0};
  float ar[8]={0,0,0,0,0,0,0,0};
  float ss = 0.f;
  if (val){
    #pragma unroll 8
    for (int c = 0; c < 64; ++c){
      float xv = __builtin_nontemporal_load(xpn + (size_t)c*TV + site);
      ss += xv;
      f4 wv0 = sW4[c*4+0], wv1 = sW4[c*4+1];
      f4 wr0 = sW4[c*4+2], wr1 = sW4[c*4+3];
      #pragma unroll
      for (int r = 0; r < 4; ++r){
        av[r]   = fmaf(wv0[r], xv, av[r]);
        av[4+r] = fmaf(wv1[r], xv, av[4+r]);
        ar[r]   = fmaf(wr0[r], xv, ar[r]);
        ar[4+r] = fmaf(wr1[r], xv, ar[4+r]);
      }
    }
  }
  if (act){
    sS[site] = ss * 0.015625f;
    #pragma unroll
    for (int r = 0; r < 8; ++r)
      sV[site*9+r] = val ? (av[r] + bv[r]) : 0.f;   // zero-pad beyond t-range
  }
  const int gbase = t0*25 - 50 + site;   // global tv offset (owned => >= 0)
  float vals[16];
  {
    float rr[8];
    if (own){
      float* rp = r0 + (size_t)n*8*TV + gbase;
      #pragma unroll
      for (int r = 0; r < 8; ++r){
        rr[r] = ar[r] + br[r];
        rp[(size_t)r*TV] = rr[r];
      }
    }
    #pragma unroll
    for (int r = 0; r < 8; ++r){
      vals[r]   = own ? rr[r] : 0.f;
      vals[8+r] = own ? rr[r]*rr[r] : 0.f;
    }
  }
  write_partials8<16>(vals, pr, NB1, red);   // internal syncs also publish sV/sS

  // Phase B: w2 (tanh) + att from LDS
  float at[8]={0,0,0,0,0,0,0,0};
  if (own){
    float m[5];
    #pragma unroll
    for (int k = 0; k < 5; ++k) m[k] = sS[site + (k-2)*25];
    float w2[5] = {0.f,0.f,0.f,0.f,0.f};
    #pragma unroll
    for (int w = 0; w < 5; ++w){
      #pragma unroll
      for (int u = 0; u < 5; ++u){
        int o = w*5 + u;
        float wo = sbw[o];
        #pragma unroll
        for (int k = 0; k < 5; ++k) wo = fmaf(sWw[o*5+k], m[k], wo);
        w2[u] += fast_tanh(wo);
      }
    }
    #pragma unroll
    for (int u = 0; u < 5; ++u){
      float wu = w2[u];
      int base = (site + (u-2)*25)*9;
      #pragma unroll
      for (int r = 0; r < 8; ++r) at[r] = fmaf(wu, sV[base + r], at[r]);
    }
    float* ap = att + (size_t)n*8*TV + gbase;
    #pragma unroll
    for (int r = 0; r < 8; ++r) ap[(size_t)r*TV] = at[r];
  }
  #pragma unroll
  for (int r = 0; r < 8; ++r){
    vals[r]   = own ? at[r] : 0.f;
    vals[8+r] = own ? at[r]*at[r] : 0.f;
  }
  write_partials8<16>(vals, patt, NB1, red);
}

// ==== K2: redundant per-block BN-coef reduce, then h = leaky(bn(att)+bn(r0)); 44 moments
// [R10-proven verbatim]
__global__ __launch_bounds__(256) void k_h(
    const float* __restrict__ att, const float* __restrict__ r0,
    const float* __restrict__ pr, const float* __restrict__ patt,
    const float* __restrict__ g_bn, const float* __restrict__ b_bn,
    const float* __restrict__ g_r, const float* __restrict__ b_r,
    float* __restrict__ h, float* __restrict__ ph)
{
  __shared__ float red[44*4];
  __shared__ float sc[32];
  const int tid = threadIdx.x;
  {
    int g = tid >> 3, l8 = tid & 7;       // 32 stats x 8 lanes
    const float* src = (g < 16) ? (pr + g*NB1) : (patt + (g-16)*NB1);
    float sm = 0.f;
    for (int k2 = l8; k2 < NB1; k2 += 8) sm += src[k2];
    sm += __shfl_down(sm, 4, 8); sm += __shfl_down(sm, 2, 8); sm += __shfl_down(sm, 1, 8);
    if (l8 == 0) red[g] = sm;
  }
  __syncthreads();
  if (tid < 8){
    int r = tid;
    float mu_r  = red[r]    / (float)NTV;
    float var_r = red[8+r]  / (float)NTV - mu_r*mu_r;
    float ar_ = g_r[r] * rsqrtf(var_r + EPSF);
    sc[16+r] = ar_; sc[24+r] = b_r[r] - ar_*mu_r;
    float mu_a  = red[16+r] / (float)NTV;
    float var_a = red[24+r] / (float)NTV - mu_a*mu_a;
    float aa = g_bn[r] * rsqrtf(var_a + EPSF);
    sc[r] = aa; sc[8+r] = b_bn[r] - aa*mu_a;
  }
  __syncthreads();

  int p = blockIdx.x*256 + tid;           // float2 site over NTV/2
  int n = p / 1600, j = p - n*1600;
  const float* ap = att + (size_t)n*8*TV + 2*j;
  const float* rp = r0  + (size_t)n*8*TV + 2*j;
  float* hp = h + (size_t)n*8*TV + 2*j;
  float h0[8], h1[8];
  #pragma unroll
  for (int r = 0; r < 8; ++r){
    float ca = sc[r], cc = sc[8+r], cr = sc[16+r], cd = sc[24+r];
    f2 a = *(const f2*)(ap + (size_t)r*TV);
    f2 rr = *(const f2*)(rp + (size_t)r*TV);
    float z0 = ca*a.x + cc + cr*rr.x + cd;
    float z1 = ca*a.y + cc + cr*rr.y + cd;
    h0[r] = (z0 >= 0.f) ? z0 : 0.1f*z0;
    h1[r] = (z1 >= 0.f) ? z1 : 0.1f*z1;
    f2 hh; hh.x = h0[r]; hh.y = h1[r];
    *(f2*)(hp + (size_t)r*TV) = hh;
  }
  float vals[44];
  #pragma unroll
  for (int r = 0; r < 8; ++r) vals[r] = h0[r] + h1[r];
  int cnt = 8;
  #pragma unroll
  for (int r = 0; r < 8; ++r){
    #pragma unroll
    for (int r2 = r; r2 < 8; ++r2) vals[cnt++] = h0[r]*h0[r2] + h1[r]*h1[r2];
  }
  write_partials4<44>(vals, ph, NB2, red);
}

// ==== K3: redundant per-block 44-stat reduce + BN fold, then out. [R10-proven verbatim]
__global__ __launch_bounds__(256) void k_out(
    const float* __restrict__ h, const float* __restrict__ ph,
    const float* __restrict__ Wo, const float* __restrict__ bo,
    const float* __restrict__ g_o, const float* __restrict__ b_o,
    float* __restrict__ out)
{
  __shared__ float hstat[44];
  __shared__ float sW[1024], sB[128];
  const int tid = threadIdx.x;
  {
    int lane = tid & 63, wid = tid >> 6;
    for (int s2 = wid; s2 < 44; s2 += 4){
      float sm = 0.f;
      for (int k2 = lane; k2 < NB2; k2 += 64) sm += ph[s2*NB2 + k2];
      #pragma unroll
      for (int o = 32; o > 0; o >>= 1) sm += __shfl_down(sm, o);
      if (lane == 0) hstat[s2] = sm;
    }
  }
  __syncthreads();
  if (tid < 128){
    int o = tid;     // one output channel each
    double muh[8];
    #pragma unroll
    for (int r = 0; r < 8; ++r) muh[r] = (double)hstat[r] / (double)NTV;
    double w[8];
    #pragma unroll
    for (int r = 0; r < 8; ++r) w[r] = (double)Wo[o*8+r];
    double bob = (double)bo[o];
    double mu = bob;
    #pragma unroll
    for (int r = 0; r < 8; ++r) mu += w[r]*muh[r];
    double t = 0.0;
    for (int r = 0; r < 8; ++r){
      for (int r2 = 0; r2 < 8; ++r2){
        int lo = (r < r2) ? r : r2, hi = (r < r2) ? r2 : r;
        int idx = 8 + lo*8 - (lo*(lo-1))/2 + (hi - lo);
        t += w[r]*w[r2]*((double)hstat[idx] / (double)NTV);
      }
    }
    double ey2 = t + 2.0*bob*(mu - bob) + bob*bob;
    double var = ey2 - mu*mu;
    double a = (double)g_o[o] / sqrt(var + (double)EPSF);
    #pragma unroll
    for (int r = 0; r < 8; ++r) sW[o*8+r] = (float)(a * w[r]);
    sB[o] = (float)(a * (bob - mu) + (double)b_o[o]);
  }
  __syncthreads();

  int p  = blockIdx.x*64 + (tid & 63);    // f4-site over NTV/4 (wave = 64 contiguous sites)
  int oq = tid >> 6;                      // o-quarter 0..3 (one wave each)
  int n = p / 800, j = p - n*800;
  const float* hp = h + (size_t)n*8*TV + 4*j;
  float hh[8][4];
  #pragma unroll
  for (int r = 0; r < 8; ++r){
    f4 v = *(const f4*)(hp + (size_t)r*TV);
    hh[r][0] = v[0]; hh[r][1] = v[1]; hh[r][2] = v[2]; hh[r][3] = v[3];
  }
  const f4* sW4 = (const f4*)sW;
  float* op = out + (size_t)n*128*TV + 4*j;
  #pragma unroll 4
  for (int oo = 0; oo < 32; ++oo){
    int o = oq*32 + oo;
    f4 w0 = sW4[o*2], w1 = sW4[o*2+1];
    float b = sB[o];
    f4 y; y.x = b; y.y = b; y.z = b; y.w = b;
    #pragma unroll
    for (int r = 0; r < 4; ++r){
      #pragma unroll
      for (int e = 0; e < 4; ++e){
        y[e] = fmaf(w0[r], hh[r][e], y[e]);
        y[e] = fmaf(w1[r], hh[4+r][e], y[e]);
      }
    }
    __builtin_nontemporal_store(y, (f4*)(op + (size_t)o*TV));
  }
}

extern "C" void kernel_launch(void* const* d_in, const int* in_sizes, int n_in,
                              void* d_out, int out_size, void* d_ws, size_t ws_size,
                              hipStream_t stream){
  const float* x    = (const float*)d_in[0];
  const float* Wv   = (const float*)d_in[1];
  const float* bv   = (const float*)d_in[2];
  const float* Ww   = (const float*)d_in[3];
  const float* bw   = (const float*)d_in[4];
  const float* g_bn = (const float*)d_in[5];
  const float* b_bn = (const float*)d_in[6];
  const float* Wr   = (const float*)d_in[7];
  const float* br   = (const float*)d_in[8];
  const float* g_r  = (const float*)d_in[9];
  const float* b_r  = (const float*)d_in[10];
  const float* Wo   = (const float*)d_in[11];
  const float* bo   = (const float*)d_in[12];
  const float* g_o  = (const float*)d_in[13];
  const float* b_o  = (const float*)d_in[14];

  float* ws = (float*)d_ws;
  size_t off = 0;
  float* r0   = ws + off; off += 1638400;   // (N,8,T,V)
  float* att  = ws + off; off += 1638400;
  float* hbuf = ws + off; off += 1638400;
  float* pr   = ws + off; off += 16*NB1;
  float* patt = ws + off; off += 16*NB1;
  float* ph   = ws + off; off += 44*NB2;

  k_pw <<<NB1, 512, 0, stream>>>(x, Wv, bv, Wr, br, Ww, bw, r0, att, pr, patt);
  k_h  <<<NB2, 256, 0, stream>>>(att, r0, pr, patt, g_bn, b_bn, g_r, b_r, hbuf, ph);
  k_out<<<NB3, 256, 0, stream>>>(hbuf, ph, Wo, bo, g_o, b_o, (float*)d_out);
}